// Round 10
// baseline (518.319 us; speedup 1.0000x reference)
//
#include <hip/hip_runtime.h>
#include <math.h>

#define BATCH 4096
#define W 4096
#define POS_NUM 10
#define NUM_NEG 30
#define SEL_PER_ROW 40   // 10 pos + 30 neg
#define TPB 256
#define SEGS 16          // segments per row (256 floats each = one wave-iteration)
#define SLOTS 16         // candidate slots per segment; P(Bin(256,.02)>16) ~ 5e-6
#define CAND_TH 0.98f    // mean ~5.1 candidates per segment, ~82 per row
#define RPB 4            // rows per topk block (1 wave per row)

typedef float f4 __attribute__((ext_vector_type(4)));

__device__ __forceinline__ void inv3x3(const double* m, double* inv) {
  double a = m[0], b = m[1], c = m[2], d = m[3], e = m[4], f = m[5],
         g = m[6], h = m[7], i = m[8];
  double A = e * i - f * h, B = f * g - d * i, C = d * h - e * g;
  double det = a * A + b * B + c * C;
  double id = 1.0 / det;
  inv[0] = A * id; inv[1] = (c * h - b * i) * id; inv[2] = (b * f - c * e) * id;
  inv[3] = B * id; inv[4] = (a * i - c * g) * id; inv[5] = (c * d - a * f) * id;
  inv[6] = C * id; inv[7] = (b * g - a * h) * id; inv[8] = (a * e - b * d) * id;
}

// ---- Kernel 1: per-row f64 matrix chain (fully parallel) + pos_row zeroing ----
__global__ __launch_bounds__(TPB) void mat_kernel(
    const float* __restrict__ gt_T, const float* __restrict__ gt_e,
    const float* __restrict__ pred_e, int* __restrict__ xmin_out,
    float* __restrict__ fl_out, float* __restrict__ pos_row) {
  int b = blockIdx.x * TPB + threadIdx.x;
  if (b >= BATCH) return;
  pos_row[b] = 0.f;
  const float* T = gt_T + (size_t)b * 16;
  const float* E = gt_e + (size_t)b * 16;
  const float* P = pred_e + (size_t)b * 16;
  double r[9], e[9], p[9];
  #pragma unroll
  for (int i = 0; i < 3; ++i)
    #pragma unroll
    for (int j = 0; j < 3; ++j) {
      r[i * 3 + j] = (double)T[i * 4 + j];
      e[i * 3 + j] = (double)E[i * 4 + j];
      p[i * 3 + j] = (double)P[i * 4 + j];
    }
  double rinv[9];
  inv3x3(r, rinv);
  double ax = p[0] * rinv[0] + p[1] * rinv[3] + p[2] * rinv[6];
  double ay = p[3] * rinv[0] + p[4] * rinv[3] + p[5] * rinv[6];
  double yaw = atan2(ay, ax);
  double fidx = (-yaw + M_PI) / (2.0 * M_PI) * (double)W;
  xmin_out[b] = (int)fidx - POS_NUM / 2;

  double m[9];
  #pragma unroll
  for (int i = 0; i < 3; ++i)
    #pragma unroll
    for (int j = 0; j < 3; ++j)
      m[i * 3 + j] = e[i * 3 + 0] * rinv[0 * 3 + j] +
                     e[i * 3 + 1] * rinv[1 * 3 + j] +
                     e[i * 3 + 2] * rinv[2 * 3 + j];
  double R[9];
  inv3x3(m, R);
  float* fl = fl_out + (size_t)b * 16;
  fl[0] = (float)R[0]; fl[1] = (float)R[1]; fl[2]  = (float)R[2]; fl[3]  = 0.f;
  fl[4] = (float)R[3]; fl[5] = (float)R[4]; fl[6]  = (float)R[5]; fl[7]  = 0.f;
  fl[8] = (float)R[6]; fl[9] = (float)R[7]; fl[10] = (float)R[8]; fl[11] = 0.f;
  fl[12] = 0.f; fl[13] = 0.f; fl[14] = 0.f; fl[15] = 1.f;
}

// ---- Kernel 2: pure streaming — gt write + atomic-free candidate spill ----
#define SBLK 2048
#define SIT 8            // SBLK*TPB*SIT == BATCH*W/4
__global__ __launch_bounds__(TPB) void stream_kernel(
    const float* __restrict__ pred, const int* __restrict__ xmin_arr,
    float* __restrict__ gt_out, int* __restrict__ cnt_seg,
    float* __restrict__ pos_row, float* __restrict__ candv) {
  int g0 = blockIdx.x * TPB + threadIdx.x;
  int lane = threadIdx.x & 63;
  const int STRIDE = SBLK * TPB;
  #pragma unroll
  for (int it = 0; it < SIT; ++it) {
    int g = g0 + it * STRIDE;          // vec4 index; wave covers one (row,seg)
    int row = g >> 10;                 // 1024 vec4 per row
    int seg = (g >> 6) & (SEGS - 1);   // 64 vec4 per segment
    int c4 = g & 1023;
    int xm = xmin_arr[row];
    f4 pv = ((const f4*)pred)[g];
    int off0 = ((c4 << 2) - xm) & (W - 1);
    float psum = 0.f;
    bool anyp = false;
    bool cd[4];
    int loc = 0;
    f4 gt;
    #pragma unroll
    for (int j = 0; j < 4; ++j) {
      bool pos = (((off0 + j) & (W - 1)) < POS_NUM);
      gt[j] = pos ? 1.f : 0.f;
      cd[j] = (!pos) && (pv[j] > CAND_TH);
      loc += cd[j] ? 1 : 0;
      if (pos) { psum += fminf(-logf(pv[j]), 100.f); anyp = true; }
    }
    ((f4*)gt_out)[g] = gt;
    if (anyp) atomicAdd(&pos_row[row], psum);   // return unused -> no wait
    // in-wave exclusive prefix scan of candidate counts (no atomics)
    int pfx = loc;
    #pragma unroll
    for (int off = 1; off < 64; off <<= 1) {
      int n = __shfl_up(pfx, off);
      pfx += (lane >= off) ? n : 0;
    }
    int total = __shfl(pfx, 63);
    int k = pfx - loc;                 // exclusive prefix
    int sbase = (row * SEGS + seg) * SLOTS;
    #pragma unroll
    for (int j = 0; j < 4; ++j)
      if (cd[j]) { if (k < SLOTS) candv[sbase + k] = pv[j]; ++k; }
    if (lane == 0) cnt_seg[row * SEGS + seg] = total;  // plain store, every seg covered once
  }
}

// ---- Kernel 3: 4 rows/block, 1 wave/row — exact top-30, throughput-oriented ----
__global__ __launch_bounds__(TPB) void topk_kernel(
    const float* __restrict__ pred, const int* __restrict__ xmin_arr,
    const int* __restrict__ cnt_seg, const float* __restrict__ pos_row,
    const float* __restrict__ candv, float* __restrict__ row_sum) {
  int wid = threadIdx.x >> 6;
  int lane = threadIdx.x & 63;
  int r = blockIdx.x * RPB + wid;
  __shared__ float sv[RPB][SEGS * SLOTS];   // 4 KB/block

  // one coalesced f4 load: the row's full 256-slot candidate array
  f4 pv = ((const f4*)(candv + (size_t)r * (SEGS * SLOTS)))[lane];
  // counts: lanes 0..15 load one each, broadcast via shfl; prefix in registers
  int cl = (lane < SEGS) ? cnt_seg[r * SEGS + lane] : 0;
  int myseg = lane >> 2;
  int myP = 0, myc = 0, Ct = 0, ov = 0;
  #pragma unroll
  for (int s = 0; s < SEGS; ++s) {
    int c_s = __shfl(cl, s);
    myP += (s < myseg) ? c_s : 0;
    myc  = (s == myseg) ? c_s : myc;
    Ct  += c_s;
    ov  |= (c_s > SLOTS) ? 1 : 0;
  }
  int slotbase = (lane & 3) * 4;
  float tsum = 0.f;

  if (!ov && Ct >= NUM_NEG) {
    // scatter-compact valid candidates into LDS (column order preserved)
    float* rl = sv[wid];
    int myidx[4];
    float vv[4];
    #pragma unroll
    for (int j = 0; j < 4; ++j) {
      bool valid = (slotbase + j < myc);
      vv[j] = valid ? pv[j] : -1.f;           // valid values are > 0.98
      myidx[j] = valid ? (myP + slotbase + j) : 0;
      if (valid) rl[myidx[j]] = pv[j];
    }
    asm volatile("s_waitcnt lgkmcnt(0)" ::: "memory");  // wave-local write->read
    int rank[4] = {0, 0, 0, 0};
    for (int k = 0; k < Ct; ++k) {
      float cv = rl[k];                       // broadcast read
      #pragma unroll
      for (int j = 0; j < 4; ++j)
        rank[j] += ((cv > vv[j]) || (cv == vv[j] && k < myidx[j])) ? 1 : 0;
    }
    #pragma unroll
    for (int j = 0; j < 4; ++j)
      if (vv[j] > 0.f && rank[j] < NUM_NEG)
        tsum += fminf(-log1pf(-vv[j]), 100.f);
    #pragma unroll
    for (int off = 32; off >= 1; off >>= 1) tsum += __shfl_xor(tsum, off);
  } else {
    // exact fallback (P ~ 1e-6): iterative max-extraction from global row
    int xm = xmin_arr[r];
    const float* prow = pred + (size_t)r * W;
    float t = 2.f;
    int taken = 0;
    while (taken < NUM_NEG) {
      float lm = -1.f;
      for (int k = lane; k < W; k += 64) {
        bool pos = (((k - xm) & (W - 1)) < POS_NUM);
        float pval = pos ? -1.f : prow[k];
        if (pval < t) lm = fmaxf(lm, pval);
      }
      #pragma unroll
      for (int off = 32; off >= 1; off >>= 1) lm = fmaxf(lm, __shfl_xor(lm, off));
      if (lm < 0.f) break;
      int lc = 0;
      for (int k = lane; k < W; k += 64) {
        bool pos = (((k - xm) & (W - 1)) < POS_NUM);
        float pval = pos ? -1.f : prow[k];
        lc += (pval == lm) ? 1 : 0;
      }
      #pragma unroll
      for (int off = 32; off >= 1; off >>= 1) lc += __shfl_xor(lc, off);
      int k2 = min(lc, NUM_NEG - taken);
      tsum += (float)k2 * fminf(-log1pf(-lm), 100.f);
      taken += k2;
      t = lm;
    }
  }
  if (lane == 0) row_sum[r] = tsum + pos_row[r];
}

// ---- Kernel 4: final reduction ----
__global__ __launch_bounds__(TPB) void reduce_kernel(
    const float* __restrict__ row_sum, float* __restrict__ out) {
  int tid = threadIdx.x;
  double acc = 0.0;
  for (int i = tid; i < BATCH; i += TPB) acc += (double)row_sum[i];
  #pragma unroll
  for (int off = 32; off >= 1; off >>= 1) acc += __shfl_xor(acc, off);
  __shared__ double sh[4];
  int wid = tid >> 6, lane = tid & 63;
  if (lane == 0) sh[wid] = acc;
  __syncthreads();
  if (tid == 0) {
    double total = sh[0] + sh[1] + sh[2] + sh[3];
    out[0] = (float)(total / (double)((size_t)SEL_PER_ROW * BATCH));
  }
}

extern "C" void kernel_launch(void* const* d_in, const int* in_sizes, int n_in,
                              void* d_out, int out_size, void* d_ws, size_t ws_size,
                              hipStream_t stream) {
  const float* gt_T   = (const float*)d_in[0];
  const float* gt_e   = (const float*)d_in[1];
  const float* pred_e = (const float*)d_in[2];
  const float* pred_f = (const float*)d_in[3];
  float* out = (float*)d_out;
  float* gt_score = out + 1;
  float* fl = out + 1 + (size_t)BATCH * W;

  int*   xmin_ws = (int*)d_ws;                         // [4096]
  float* pos_row = (float*)(xmin_ws + BATCH);          // [4096]
  float* row_sum = pos_row + BATCH;                    // [4096]
  int*   cnt_seg = (int*)(row_sum + BATCH);            // [4096*16]
  float* candv   = (float*)(cnt_seg + BATCH * SEGS);   // [4096*16*16]

  mat_kernel<<<BATCH / TPB, TPB, 0, stream>>>(gt_T, gt_e, pred_e, xmin_ws, fl,
                                              pos_row);
  stream_kernel<<<SBLK, TPB, 0, stream>>>(pred_f, xmin_ws, gt_score, cnt_seg,
                                          pos_row, candv);
  topk_kernel<<<BATCH / RPB, TPB, 0, stream>>>(pred_f, xmin_ws, cnt_seg,
                                               pos_row, candv, row_sum);
  reduce_kernel<<<1, TPB, 0, stream>>>(row_sum, out);
}

// Round 11
// 129.943 us; speedup vs baseline: 3.9888x; 3.9888x over previous
//
#include <hip/hip_runtime.h>
#include <math.h>

#define BATCH 4096
#define W 4096
#define POS_NUM 10
#define NUM_NEG 30
#define SEL_PER_ROW 40   // 10 pos + 30 neg
#define TPB 256
#define CAP 256          // candidate buffer (1 KB LDS); mean ~61, P(>256)=0
#define CAND_TH 0.985f   // P(cnt<30) ~ 2e-5 per row -> exact fallback

typedef float f4 __attribute__((ext_vector_type(4)));

__device__ __forceinline__ void inv3x3(const double* m, double* inv) {
  double a = m[0], b = m[1], c = m[2], d = m[3], e = m[4], f = m[5],
         g = m[6], h = m[7], i = m[8];
  double A = e * i - f * h, B = f * g - d * i, C = d * h - e * g;
  double det = a * A + b * B + c * C;
  double id = 1.0 / det;
  inv[0] = A * id; inv[1] = (c * h - b * i) * id; inv[2] = (b * f - c * e) * id;
  inv[3] = B * id; inv[4] = (a * i - c * g) * id; inv[5] = (c * d - a * f) * id;
  inv[6] = C * id; inv[7] = (b * g - a * h) * id; inv[8] = (a * e - b * d) * id;
}

// ---- Kernel 1: per-row f64 matrix chain (fully parallel) ----
__global__ __launch_bounds__(TPB) void mat_kernel(
    const float* __restrict__ gt_T, const float* __restrict__ gt_e,
    const float* __restrict__ pred_e, int* __restrict__ xmin_out,
    float* __restrict__ fl_out) {
  int b = blockIdx.x * TPB + threadIdx.x;
  if (b >= BATCH) return;
  const float* T = gt_T + (size_t)b * 16;
  const float* E = gt_e + (size_t)b * 16;
  const float* P = pred_e + (size_t)b * 16;
  double r[9], e[9], p[9];
  #pragma unroll
  for (int i = 0; i < 3; ++i)
    #pragma unroll
    for (int j = 0; j < 3; ++j) {
      r[i * 3 + j] = (double)T[i * 4 + j];
      e[i * 3 + j] = (double)E[i * 4 + j];
      p[i * 3 + j] = (double)P[i * 4 + j];
    }
  double rinv[9];
  inv3x3(r, rinv);
  double ax = p[0] * rinv[0] + p[1] * rinv[3] + p[2] * rinv[6];
  double ay = p[3] * rinv[0] + p[4] * rinv[3] + p[5] * rinv[6];
  double yaw = atan2(ay, ax);
  double fidx = (-yaw + M_PI) / (2.0 * M_PI) * (double)W;
  xmin_out[b] = (int)fidx - POS_NUM / 2;

  double m[9];
  #pragma unroll
  for (int i = 0; i < 3; ++i)
    #pragma unroll
    for (int j = 0; j < 3; ++j)
      m[i * 3 + j] = e[i * 3 + 0] * rinv[0 * 3 + j] +
                     e[i * 3 + 1] * rinv[1 * 3 + j] +
                     e[i * 3 + 2] * rinv[2 * 3 + j];
  double R[9];
  inv3x3(m, R);
  float* fl = fl_out + (size_t)b * 16;
  fl[0] = (float)R[0]; fl[1] = (float)R[1]; fl[2]  = (float)R[2]; fl[3]  = 0.f;
  fl[4] = (float)R[3]; fl[5] = (float)R[4]; fl[6]  = (float)R[5]; fl[7]  = 0.f;
  fl[8] = (float)R[6]; fl[9] = (float)R[7]; fl[10] = (float)R[8]; fl[11] = 0.f;
  fl[12] = 0.f; fl[13] = 0.f; fl[14] = 0.f; fl[15] = 1.f;
}

// ---- Kernel 2: fused per-row streaming + exact top-30 (round-3 structure) ----
__global__ __launch_bounds__(TPB) void row_kernel(
    const float* __restrict__ pred, const int* __restrict__ xmin_arr,
    float* __restrict__ gt_out, float* __restrict__ row_sum) {
  int b = blockIdx.x;
  int tid = threadIdx.x;
  __shared__ float cand[CAP];          // 1 KB
  __shared__ unsigned s_cnt;
  __shared__ float s_red[TPB / 64];
  if (tid == 0) s_cnt = 0;
  int xmin = xmin_arr[b];              // broadcast load, no barrier needed

  const f4* prow = (const f4*)(pred + (size_t)b * W);
  f4 pv[4];
  #pragma unroll
  for (int k = 0; k < 4; ++k) pv[k] = prow[tid + k * TPB];

  __syncthreads();                     // s_cnt=0 visible before appends

  f4* grow = (f4*)(gt_out + (size_t)b * W);
  float pp[16];                        // raw p; positives -> -3 (never selected)
  float pos_sum = 0.f;
  #pragma unroll
  for (int k = 0; k < 4; ++k) {
    int w0 = (tid + k * TPB) * 4;
    f4 gt;
    #pragma unroll
    for (int j = 0; j < 4; ++j) {
      float p = pv[k][j];
      bool q = (((w0 + j - xmin) & (W - 1)) < POS_NUM);
      gt[j] = q ? 1.f : 0.f;
      if (q) { pos_sum += fminf(-logf(p), 100.f); p = -3.f; }
      pp[k * 4 + j] = p;
    }
    __builtin_nontemporal_store(gt, grow + (tid + k * TPB));
  }

  // candidate append (raw p > threshold); LDS atomic on one counter
  int loc = 0;
  #pragma unroll
  for (int j = 0; j < 16; ++j) loc += (pp[j] > CAND_TH) ? 1 : 0;
  if (loc) {
    unsigned base = atomicAdd(&s_cnt, (unsigned)loc);
    #pragma unroll
    for (int j = 0; j < 16; ++j)
      if (pp[j] > CAND_TH) { if (base < CAP) cand[base] = pp[j]; ++base; }
  }

  // block-reduce pos_sum
  float s = pos_sum;
  #pragma unroll
  for (int off = 32; off >= 1; off >>= 1) s += __shfl_xor(s, off);
  if ((tid & 63) == 0) s_red[tid >> 6] = s;
  __syncthreads();                     // appends + s_cnt + s_red visible
  unsigned C = s_cnt;
  float posT = s_red[0] + s_red[1] + s_red[2] + s_red[3];

  if (C >= NUM_NEG && C <= CAP) {
    // wave 0: exact stable-rank top-30 over candidates (ties sum-equivalent)
    if (tid < 64) {
      float tsum = 0.f;
      for (unsigned base0 = 0; base0 < C; base0 += 64) {
        unsigned myi = base0 + (unsigned)tid;
        bool valid = (myi < C);
        float mine = valid ? cand[myi] : -1.f;
        int rank = valid ? 0 : NUM_NEG;
        for (unsigned j = 0; j < C; ++j) {
          float cj = cand[j];
          rank += ((cj > mine) || (cj == mine && j < myi)) ? 1 : 0;
        }
        if (rank < NUM_NEG) tsum += fminf(-log1pf(-mine), 100.f);
      }
      #pragma unroll
      for (int off = 32; off >= 1; off >>= 1) tsum += __shfl_xor(tsum, off);
      if (tid == 0) row_sum[b] = tsum + posT;
    }
  } else {
    // exact fallback (P ~ 2e-5/row): block-wide max-extraction from registers
    float t = 2.f;
    int taken = 0;
    float acc = 0.f;
    while (taken < NUM_NEG) {
      float lm = -1.f;
      #pragma unroll
      for (int j = 0; j < 16; ++j)
        if (pp[j] < t) lm = fmaxf(lm, pp[j]);
      #pragma unroll
      for (int off = 32; off >= 1; off >>= 1) lm = fmaxf(lm, __shfl_xor(lm, off));
      if ((tid & 63) == 0) s_red[tid >> 6] = lm;
      __syncthreads();
      float bm = fmaxf(fmaxf(s_red[0], s_red[1]), fmaxf(s_red[2], s_red[3]));
      __syncthreads();                 // s_red reuse protection
      if (bm < 0.f) break;             // fewer negatives than NUM_NEG (impossible here)
      int lc = 0;
      #pragma unroll
      for (int j = 0; j < 16; ++j) lc += (pp[j] == bm) ? 1 : 0;
      #pragma unroll
      for (int off = 32; off >= 1; off >>= 1) lc += __shfl_xor(lc, off);
      if ((tid & 63) == 0) s_red[tid >> 6] = (float)lc;
      __syncthreads();
      int bc = (int)(s_red[0] + s_red[1] + s_red[2] + s_red[3]);
      __syncthreads();
      int k2 = min(bc, NUM_NEG - taken);
      acc += (float)k2 * fminf(-log1pf(-bm), 100.f);
      taken += k2;
      t = bm;
    }
    if (tid == 0) row_sum[b] = acc + posT;
  }
}

// ---- Kernel 3: final reduction ----
__global__ __launch_bounds__(TPB) void reduce_kernel(
    const float* __restrict__ row_sum, float* __restrict__ out) {
  int tid = threadIdx.x;
  double acc = 0.0;
  for (int i = tid; i < BATCH; i += TPB) acc += (double)row_sum[i];
  #pragma unroll
  for (int off = 32; off >= 1; off >>= 1) acc += __shfl_xor(acc, off);
  __shared__ double sh[4];
  int wid = tid >> 6, lane = tid & 63;
  if (lane == 0) sh[wid] = acc;
  __syncthreads();
  if (tid == 0) {
    double total = sh[0] + sh[1] + sh[2] + sh[3];
    out[0] = (float)(total / (double)((size_t)SEL_PER_ROW * BATCH));
  }
}

extern "C" void kernel_launch(void* const* d_in, const int* in_sizes, int n_in,
                              void* d_out, int out_size, void* d_ws, size_t ws_size,
                              hipStream_t stream) {
  const float* gt_T   = (const float*)d_in[0];
  const float* gt_e   = (const float*)d_in[1];
  const float* pred_e = (const float*)d_in[2];
  const float* pred_f = (const float*)d_in[3];
  float* out = (float*)d_out;
  float* gt_score = out + 1;
  float* fl = out + 1 + (size_t)BATCH * W;

  int*   xmin_ws = (int*)d_ws;                 // [4096]
  float* row_sum = (float*)(xmin_ws + BATCH);  // [4096]

  mat_kernel<<<BATCH / TPB, TPB, 0, stream>>>(gt_T, gt_e, pred_e, xmin_ws, fl);
  row_kernel<<<BATCH, TPB, 0, stream>>>(pred_f, xmin_ws, gt_score, row_sum);
  reduce_kernel<<<1, TPB, 0, stream>>>(row_sum, out);
}